// Round 1
// baseline (1150.330 us; speedup 1.0000x reference)
//
#include <hip/hip_runtime.h>
#include <hip/hip_bf16.h>

// SCAN similarity: out[i,c] = t2i[c,i] + i2t[c,i]
// g (global sim) cancels in the renormalization -> img_mean/cap_mean unused.

#define EPSF 1e-8f
#define LAMF 9.0f

constexpr int IN = 128, CN = 128, RN = 36, WN = 48, DN = 1024;
constexpr int DCH = 64;     // D chunk staged in LDS
constexpr int RP  = 48;     // img rows padded to 48 (rows 36..47 zero)
constexpr int PITCH = 68;   // chunk row pitch in floats (+4 pad breaks bank stride)

__device__ __forceinline__ float leaky(float x) { return x > 0.f ? x : 0.1f * x; }

__device__ __forceinline__ void fma4(float4& acc, const float4 a, const float4 b) {
    acc.x = fmaf(a.x, b.x, acc.x);
    acc.y = fmaf(a.y, b.y, acc.y);
    acc.z = fmaf(a.z, b.z, acc.z);
    acc.w = fmaf(a.w, b.w, acc.w);
}

__global__ __launch_bounds__(256, 4) void scan_fused(
    const float* __restrict__ img_emb,   // [128][36][1024]
    const float* __restrict__ cap_emb,   // [128][48][1024]
    float* __restrict__ out)             // [128][128], out[i*128+c]
{
    __shared__ float s_img[RP][PITCH];
    __shared__ float s_cap[WN][PITCH];
    __shared__ float s_S[RN][WN + 1];
    __shared__ float s_nrow[RN];
    __shared__ float s_ncol[WN];
    __shared__ float s_cw[WN];
    __shared__ float s_cr[RN];

    const int t = threadIdx.x;
    const int c = blockIdx.x & (CN - 1);
    const int i = blockIdx.x >> 7;

    const float* imgB = img_emb + (size_t)i * RN * DN;
    const float* capB = cap_emb + (size_t)c * WN * DN;

    const int ty = t >> 4;   // 0..15 -> rows ty, ty+16, ty+32
    const int tx = t & 15;   // 0..15 -> cols tx, tx+16, tx+32

    float4 acc[3][3];
#pragma unroll
    for (int a = 0; a < 3; ++a)
#pragma unroll
        for (int b = 0; b < 3; ++b) acc[a][b] = make_float4(0.f, 0.f, 0.f, 0.f);

    for (int d0 = 0; d0 < DN; d0 += DCH) {
        // stage img chunk (48 rows x 64 floats; rows >= 36 zeroed)
#pragma unroll
        for (int p = 0; p < 3; ++p) {
            int idx = t + p * 256;        // 0..767 float4 slots
            int row = idx >> 4;
            int col = (idx & 15) << 2;
            float4 v = make_float4(0.f, 0.f, 0.f, 0.f);
            if (row < RN) v = *(const float4*)(imgB + row * DN + d0 + col);
            *(float4*)&s_img[row][col] = v;
        }
        // stage cap chunk (48 rows x 64 floats)
#pragma unroll
        for (int p = 0; p < 3; ++p) {
            int idx = t + p * 256;
            int row = idx >> 4;
            int col = (idx & 15) << 2;
            *(float4*)&s_cap[row][col] = *(const float4*)(capB + row * DN + d0 + col);
        }
        __syncthreads();

        for (int d = 0; d < DCH; d += 4) {
            float4 a0 = *(float4*)&s_img[ty     ][d];
            float4 a1 = *(float4*)&s_img[ty + 16][d];
            float4 a2 = *(float4*)&s_img[ty + 32][d];
            float4 b0 = *(float4*)&s_cap[tx     ][d];
            float4 b1 = *(float4*)&s_cap[tx + 16][d];
            float4 b2 = *(float4*)&s_cap[tx + 32][d];
            fma4(acc[0][0], a0, b0); fma4(acc[0][1], a0, b1); fma4(acc[0][2], a0, b2);
            fma4(acc[1][0], a1, b0); fma4(acc[1][1], a1, b1); fma4(acc[1][2], a1, b2);
            fma4(acc[2][0], a2, b0); fma4(acc[2][1], a2, b1); fma4(acc[2][2], a2, b2);
        }
        __syncthreads();
    }

    // write S tile (real rows only)
#pragma unroll
    for (int a = 0; a < 3; ++a) {
        int r = ty + 16 * a;
        if (r < RN) {
#pragma unroll
            for (int b = 0; b < 3; ++b) {
                int w = tx + 16 * b;
                float4 v = acc[a][b];
                s_S[r][w] = (v.x + v.y) + (v.z + v.w);
            }
        }
    }
    __syncthreads();

    // l2 norms: n_row[r] over w (for t2i), n_col[w] over r (for i2t)
    if (t < RN) {
        int r = t; float ss = 0.f;
        for (int w = 0; w < WN; ++w) { float l = leaky(s_S[r][w]); ss = fmaf(l, l, ss); }
        s_nrow[r] = sqrtf(ss + EPSF) + EPSF;
    } else if (t >= 64 && t < 64 + WN) {
        int w = t - 64; float ss = 0.f;
        for (int r = 0; r < RN; ++r) { float l = leaky(s_S[r][w]); ss = fmaf(l, l, ss); }
        s_ncol[w] = sqrtf(ss + EPSF) + EPSF;
    }
    __syncthreads();

    if (t < RN) {
        // i2t: per row r, softmax over w of LAM * leaky(S)/n_col[w], weighted by S
        int r = t;
        float m = -1e30f;
        for (int w = 0; w < WN; ++w) {
            float b = LAMF * leaky(s_S[r][w]) / s_ncol[w];
            m = fmaxf(m, b);
        }
        float se = 0.f, swS = 0.f;
        for (int w = 0; w < WN; ++w) {
            float b = LAMF * leaky(s_S[r][w]) / s_ncol[w];
            float e = __expf(b - m);
            se += e;
            swS = fmaf(e, s_S[r][w], swS);
        }
        s_cr[r] = swS / se;
    } else if (t >= 64 && t < 64 + WN) {
        // t2i: per col w, softmax over r of LAM * leaky(S)/n_row[r], weighted by S
        int w = t - 64;
        float m = -1e30f;
        for (int r = 0; r < RN; ++r) {
            float a = LAMF * leaky(s_S[r][w]) / s_nrow[r];
            m = fmaxf(m, a);
        }
        float se = 0.f, swS = 0.f;
        for (int r = 0; r < RN; ++r) {
            float a = LAMF * leaky(s_S[r][w]) / s_nrow[r];
            float e = __expf(a - m);
            se += e;
            swS = fmaf(e, s_S[r][w], swS);
        }
        s_cw[w] = swS / se;
    }
    __syncthreads();

    if (t == 0) {
        float t2i = 0.f, i2t = 0.f;
        for (int w = 0; w < WN; ++w) t2i += s_cw[w];
        for (int r = 0; r < RN; ++r) i2t += s_cr[r];
        out[(size_t)i * CN + c] = t2i / (float)WN + i2t / (float)RN;
    }
}

extern "C" void kernel_launch(void* const* d_in, const int* in_sizes, int n_in,
                              void* d_out, int out_size, void* d_ws, size_t ws_size,
                              hipStream_t stream) {
    const float* img_emb = (const float*)d_in[0];
    const float* cap_emb = (const float*)d_in[2];
    float* out = (float*)d_out;
    hipLaunchKernelGGL(scan_fused, dim3(IN * CN), dim3(256), 0, stream,
                       img_emb, cap_emb, out);
}

// Round 2
// 335.019 us; speedup vs baseline: 3.4336x; 3.4336x over previous
//
#include <hip/hip_runtime.h>
#include <hip/hip_bf16.h>

// SCAN similarity: out[i,c] = t2i[c,i] + i2t[c,i]
// g (global sim) cancels in the renormalization -> img_mean/cap_mean unused.
// bf16-MFMA path: S tiles via v_mfma_f32_16x16x32_bf16, softmax phase in LDS.

#define EPSF 1e-8f
#define LAMF 9.0f

constexpr int IN = 128, CN = 128, RN = 36, WN = 48, DN = 1024;

using short8 = __attribute__((ext_vector_type(8))) short;
using f32x4  = __attribute__((ext_vector_type(4))) float;

__device__ __forceinline__ float leaky(float x) { return x > 0.f ? x : 0.1f * x; }

__device__ __forceinline__ unsigned short f2bf(float f) {
    unsigned int b = __float_as_uint(f);
    b += 0x7FFFu + ((b >> 16) & 1u);          // round-to-nearest-even
    return (unsigned short)(b >> 16);
}

// ---------- preprocess: f32 -> bf16 ----------
__global__ void cvt_bf16(const float* __restrict__ in, unsigned short* __restrict__ out, int n4) {
    int idx = blockIdx.x * blockDim.x + threadIdx.x;
    if (idx >= n4) return;
    float4 v = ((const float4*)in)[idx];
    ushort4 o;
    o.x = f2bf(v.x); o.y = f2bf(v.y); o.z = f2bf(v.z); o.w = f2bf(v.w);
    ((ushort4*)out)[idx] = o;
}

// ---------- main MFMA kernel ----------
// block: 1 image i x 8 captions (c0..c0+7); 4 waves; wave w owns captions c0+2w, c0+2w+1.
// Per wave: S panel 48 rows (36 real, zero-padded) x 96 cols, 16x16x32 MFMA,
// 3 row-tiles x 6 col-tiles.
__global__ __launch_bounds__(256, 2) void scan_mfma(
    const unsigned short* __restrict__ imgh,  // [128][36][1024] bf16 bits
    const unsigned short* __restrict__ caph,  // [128][48][1024] bf16 bits
    float* __restrict__ out)                  // [128][128], out[i*128+c]
{
    // LDS plan (union via byte buffer):
    //   staging: simg[48][72] (6912 B) | scap[384][72] (55296 B)   total 62208
    //   phase2 : sS[8][36][49] f32 (56448) | nrow 1152 | ncol 1536 | cr 1152 | cw 1536
    __shared__ __align__(16) unsigned char smem[62208];
    unsigned short (*simg)[72] = (unsigned short (*)[72])smem;
    unsigned short (*scap)[72] = (unsigned short (*)[72])(smem + 6912);
    float (*sS)[RN][WN + 1] = (float (*)[RN][WN + 1])smem;
    float* snrow = (float*)(smem + 56448);   // [8][36]
    float* sncol = (float*)(smem + 57600);   // [8][48]
    float* scr   = (float*)(smem + 59136);   // [8][36]
    float* scw   = (float*)(smem + 60288);   // [8][48]

    const int t    = threadIdx.x;
    const int lane = t & 63;
    const int wid  = t >> 6;      // 0..3
    const int lr   = lane & 15;
    const int lg   = lane >> 4;   // 0..3

    const int i  = blockIdx.y;
    const int c0 = blockIdx.x * 8;

    const unsigned short* imgB = imgh + (size_t)i  * RN * DN;
    const unsigned short* capB = caph + (size_t)c0 * WN * DN;

    f32x4 acc[3][6];
#pragma unroll
    for (int rt = 0; rt < 3; ++rt)
#pragma unroll
        for (int ct = 0; ct < 6; ++ct) acc[rt][ct] = (f32x4)(0.f);

    for (int d0 = 0; d0 < DN; d0 += 64) {
        // stage img chunk: 48 rows x 64 bf16 (rows >= 36 zero)
#pragma unroll
        for (int u = t; u < 384; u += 256) {
            int row = u >> 3, c8 = (u & 7) << 3;
            uint4 v = make_uint4(0u, 0u, 0u, 0u);
            if (row < RN) v = *(const uint4*)(imgB + (size_t)row * DN + d0 + c8);
            *(uint4*)&simg[row][c8] = v;
        }
        // stage cap chunk: 384 rows (8 captions x 48) x 64 bf16
#pragma unroll
        for (int u = t; u < 3072; u += 256) {
            int row = u >> 3, c8 = (u & 7) << 3;
            *(uint4*)&scap[row][c8] = *(const uint4*)(capB + (size_t)row * DN + d0 + c8);
        }
        __syncthreads();

#pragma unroll
        for (int ks = 0; ks < 2; ++ks) {
            const int kb = ks * 32 + lg * 8;
            short8 a0 = *(const short8*)&simg[ 0 + lr][kb];
            short8 a1 = *(const short8*)&simg[16 + lr][kb];
            short8 a2 = *(const short8*)&simg[32 + lr][kb];
            short8 b[6];
#pragma unroll
            for (int ct = 0; ct < 6; ++ct)
                b[ct] = *(const short8*)&scap[wid * 96 + ct * 16 + lr][kb];
#pragma unroll
            for (int ct = 0; ct < 6; ++ct) {
                acc[0][ct] = __builtin_amdgcn_mfma_f32_16x16x32_bf16(a0, b[ct], acc[0][ct], 0, 0, 0);
                acc[1][ct] = __builtin_amdgcn_mfma_f32_16x16x32_bf16(a1, b[ct], acc[1][ct], 0, 0, 0);
                acc[2][ct] = __builtin_amdgcn_mfma_f32_16x16x32_bf16(a2, b[ct], acc[2][ct], 0, 0, 0);
            }
        }
        __syncthreads();
    }

    // write S tiles to LDS (aliases staging; all reads are behind the last barrier)
    // C/D layout: col = lane&15, row = (lane>>4)*4 + reg   [m89-verified]
#pragma unroll
    for (int rt = 0; rt < 3; ++rt)
#pragma unroll
        for (int ct = 0; ct < 6; ++ct) {
            int cap = wid * 2 + ct / 3;
            int col = (ct % 3) * 16 + lr;
#pragma unroll
            for (int r = 0; r < 4; ++r) {
                int row = rt * 16 + lg * 4 + r;
                if (row < RN) sS[cap][row][col] = acc[rt][ct][r];
            }
        }
    __syncthreads();

    // ---- phase 2: per caption, l2 norms then softmax-weighted sums ----
    // col norms over r (for t2i)
    for (int idx = t; idx < 8 * WN; idx += 256) {
        int cap = idx / WN, w = idx % WN;
        float ss = 0.f;
        for (int r = 0; r < RN; ++r) { float l = leaky(sS[cap][r][w]); ss = fmaf(l, l, ss); }
        sncol[idx] = sqrtf(ss + EPSF) + EPSF;
    }
    // row norms over w (for i2t)
    for (int idx = t; idx < 8 * RN; idx += 256) {
        int cap = idx / RN, r = idx % RN;
        float ss = 0.f;
        for (int w = 0; w < WN; ++w) { float l = leaky(sS[cap][r][w]); ss = fmaf(l, l, ss); }
        snrow[idx] = sqrtf(ss + EPSF) + EPSF;
    }
    __syncthreads();

    // i2t: per row r, softmax over w of LAM*leaky(S)/ncol[w], weighted by S
    for (int idx = t; idx < 8 * RN; idx += 256) {
        int cap = idx / RN, r = idx % RN;
        const float* Sr = sS[cap][r];
        const float* nc = sncol + cap * WN;
        float m = -1e30f;
        for (int w = 0; w < WN; ++w) m = fmaxf(m, leaky(Sr[w]) / nc[w]);
        m *= LAMF;
        float se = 0.f, sw = 0.f;
        for (int w = 0; w < WN; ++w) {
            float e = __expf(LAMF * leaky(Sr[w]) / nc[w] - m);
            se += e;
            sw = fmaf(e, Sr[w], sw);
        }
        scr[idx] = sw / se;
    }
    // t2i: per col w, softmax over r of LAM*leaky(S)/nrow[r], weighted by S
    for (int idx = t; idx < 8 * WN; idx += 256) {
        int cap = idx / WN, w = idx % WN;
        const float* nr = snrow + cap * RN;
        float m = -1e30f;
        for (int r = 0; r < RN; ++r) m = fmaxf(m, leaky(sS[cap][r][w]) / nr[r]);
        m *= LAMF;
        float se = 0.f, sw = 0.f;
        for (int r = 0; r < RN; ++r) {
            float s = sS[cap][r][w];
            float e = __expf(LAMF * leaky(s) / nr[r] - m);
            se += e;
            sw = fmaf(e, s, sw);
        }
        scw[idx] = sw / se;
    }
    __syncthreads();

    if (t < 8) {
        float t2i = 0.f, i2t = 0.f;
        for (int w = 0; w < WN; ++w) t2i += scw[t * WN + w];
        for (int r = 0; r < RN; ++r) i2t += scr[t * RN + r];
        out[(size_t)i * CN + (c0 + t)] = t2i / (float)WN + i2t / (float)RN;
    }
}

// ---------- fp32 fallback (round-1 kernel, used only if ws too small) ----------
__global__ __launch_bounds__(256, 4) void scan_fused(
    const float* __restrict__ img_emb, const float* __restrict__ cap_emb,
    float* __restrict__ out)
{
    __shared__ float s_img[48][68];
    __shared__ float s_cap[48][68];
    __shared__ float s_S[RN][WN + 1];
    __shared__ float s_nrow[RN];
    __shared__ float s_ncol[WN];
    __shared__ float s_cw[WN];
    __shared__ float s_cr[RN];

    const int t = threadIdx.x;
    const int c = blockIdx.x & (CN - 1);
    const int i = blockIdx.x >> 7;
    const float* imgB = img_emb + (size_t)i * RN * DN;
    const float* capB = cap_emb + (size_t)c * WN * DN;
    const int ty = t >> 4, tx = t & 15;

    float4 acc[3][3];
#pragma unroll
    for (int a = 0; a < 3; ++a)
#pragma unroll
        for (int b = 0; b < 3; ++b) acc[a][b] = make_float4(0.f, 0.f, 0.f, 0.f);

    for (int d0 = 0; d0 < DN; d0 += 64) {
#pragma unroll
        for (int p = 0; p < 3; ++p) {
            int idx = t + p * 256, row = idx >> 4, col = (idx & 15) << 2;
            float4 v = make_float4(0.f, 0.f, 0.f, 0.f);
            if (row < RN) v = *(const float4*)(imgB + row * DN + d0 + col);
            *(float4*)&s_img[row][col] = v;
        }
#pragma unroll
        for (int p = 0; p < 3; ++p) {
            int idx = t + p * 256, row = idx >> 4, col = (idx & 15) << 2;
            *(float4*)&s_cap[row][col] = *(const float4*)(capB + row * DN + d0 + col);
        }
        __syncthreads();
        for (int d = 0; d < 64; d += 4) {
            float4 a0 = *(float4*)&s_img[ty][d], a1 = *(float4*)&s_img[ty + 16][d], a2 = *(float4*)&s_img[ty + 32][d];
            float4 b0 = *(float4*)&s_cap[tx][d], b1 = *(float4*)&s_cap[tx + 16][d], b2 = *(float4*)&s_cap[tx + 32][d];
#define F4(ac, aa, bb) ac.x=fmaf(aa.x,bb.x,ac.x); ac.y=fmaf(aa.y,bb.y,ac.y); ac.z=fmaf(aa.z,bb.z,ac.z); ac.w=fmaf(aa.w,bb.w,ac.w)
            F4(acc[0][0],a0,b0); F4(acc[0][1],a0,b1); F4(acc[0][2],a0,b2);
            F4(acc[1][0],a1,b0); F4(acc[1][1],a1,b1); F4(acc[1][2],a1,b2);
            F4(acc[2][0],a2,b0); F4(acc[2][1],a2,b1); F4(acc[2][2],a2,b2);
#undef F4
        }
        __syncthreads();
    }
#pragma unroll
    for (int a = 0; a < 3; ++a) {
        int r = ty + 16 * a;
        if (r < RN)
#pragma unroll
            for (int b = 0; b < 3; ++b) {
                float4 v = acc[a][b];
                s_S[r][tx + 16 * b] = (v.x + v.y) + (v.z + v.w);
            }
    }
    __syncthreads();
    if (t < RN) {
        float ss = 0.f;
        for (int w = 0; w < WN; ++w) { float l = leaky(s_S[t][w]); ss = fmaf(l, l, ss); }
        s_nrow[t] = sqrtf(ss + EPSF) + EPSF;
    } else if (t >= 64 && t < 64 + WN) {
        int w = t - 64; float ss = 0.f;
        for (int r = 0; r < RN; ++r) { float l = leaky(s_S[r][w]); ss = fmaf(l, l, ss); }
        s_ncol[w] = sqrtf(ss + EPSF) + EPSF;
    }
    __syncthreads();
    if (t < RN) {
        float m = -1e30f;
        for (int w = 0; w < WN; ++w) m = fmaxf(m, LAMF * leaky(s_S[t][w]) / s_ncol[w]);
        float se = 0.f, sw = 0.f;
        for (int w = 0; w < WN; ++w) {
            float e = __expf(LAMF * leaky(s_S[t][w]) / s_ncol[w] - m);
            se += e; sw = fmaf(e, s_S[t][w], sw);
        }
        s_cr[t] = sw / se;
    } else if (t >= 64 && t < 64 + WN) {
        int w = t - 64; float m = -1e30f;
        for (int r = 0; r < RN; ++r) m = fmaxf(m, LAMF * leaky(s_S[r][w]) / s_nrow[r]);
        float se = 0.f, sw = 0.f;
        for (int r = 0; r < RN; ++r) {
            float e = __expf(LAMF * leaky(s_S[r][w]) / s_nrow[r] - m);
            se += e; sw = fmaf(e, s_S[r][w], sw);
        }
        s_cw[w] = sw / se;
    }
    __syncthreads();
    if (t == 0) {
        float t2i = 0.f, i2t = 0.f;
        for (int w = 0; w < WN; ++w) t2i += s_cw[w];
        for (int r = 0; r < RN; ++r) i2t += s_cr[r];
        out[(size_t)i * CN + c] = t2i / (float)WN + i2t / (float)RN;
    }
}

extern "C" void kernel_launch(void* const* d_in, const int* in_sizes, int n_in,
                              void* d_out, int out_size, void* d_ws, size_t ws_size,
                              hipStream_t stream) {
    const float* img = (const float*)d_in[0];
    const float* cap = (const float*)d_in[2];
    float* out = (float*)d_out;

    const size_t n_img = (size_t)IN * RN * DN;   // 4718592
    const size_t n_cap = (size_t)CN * WN * DN;   // 6291456
    const size_t need  = (n_img + n_cap) * 2;

    if (ws_size >= need) {
        unsigned short* imgh = (unsigned short*)d_ws;
        unsigned short* caph = imgh + n_img;
        int n4i = (int)(n_img / 4), n4c = (int)(n_cap / 4);
        hipLaunchKernelGGL(cvt_bf16, dim3((n4i + 255) / 256), dim3(256), 0, stream, img, imgh, n4i);
        hipLaunchKernelGGL(cvt_bf16, dim3((n4c + 255) / 256), dim3(256), 0, stream, cap, caph, n4c);
        hipLaunchKernelGGL(scan_mfma, dim3(CN / 8, IN), dim3(256), 0, stream, imgh, caph, out);
    } else {
        hipLaunchKernelGGL(scan_fused, dim3(IN * CN), dim3(256), 0, stream, img, cap, out);
    }
}

// Round 3
// 217.503 us; speedup vs baseline: 5.2888x; 1.5403x over previous
//
#include <hip/hip_runtime.h>
#include <hip/hip_bf16.h>

// SCAN similarity: out[i,c] = t2i[c,i] + i2t[c,i]
// g (global sim) cancels in the renormalization -> img_mean/cap_mean unused.
// bf16 MFMA + global_load_lds double-buffered pipeline + XOR-swizzled LDS.

#define EPSF 1e-8f
#define LAMF 9.0f

constexpr int IN = 128, CN = 128, RN = 36, WN = 48, DN = 1024;

using short8 = __attribute__((ext_vector_type(8))) short;
using f32x4  = __attribute__((ext_vector_type(4))) float;

__device__ __forceinline__ float leaky(float x) { return x > 0.f ? x : 0.1f * x; }

__device__ __forceinline__ unsigned short f2bf(float f) {
    unsigned int b = __float_as_uint(f);
    b += 0x7FFFu + ((b >> 16) & 1u);          // round-to-nearest-even
    return (unsigned short)(b >> 16);
}

__device__ __forceinline__ void gld_lds16(const unsigned short* g, void* l) {
    __builtin_amdgcn_global_load_lds(
        (const __attribute__((address_space(1))) unsigned int*)g,
        (__attribute__((address_space(3))) unsigned int*)l,
        16, 0, 0);
}

// ---------- preprocess: f32 -> bf16 ----------
__global__ void cvt_bf16(const float* __restrict__ in, unsigned short* __restrict__ out, int n4) {
    int idx = blockIdx.x * blockDim.x + threadIdx.x;
    if (idx >= n4) return;
    float4 v = ((const float4*)in)[idx];
    ushort4 o;
    o.x = f2bf(v.x); o.y = f2bf(v.y); o.z = f2bf(v.z); o.w = f2bf(v.w);
    ((ushort4*)out)[idx] = o;
}

// ---------- main MFMA kernel ----------
// block = 1 image (blockIdx.x) x 8 captions (blockIdx.y*8..+7); 4 waves.
// Wave w owns captions c0+2w, c0+2w+1 : S panel 48(rows, 36 real) x 96(cols).
// K chunk = 32 elems. LDS rows are 64 B = 4 x 16B granules, XOR-swizzled by
// (row>>1)&3 on BOTH the global source (stage) and the ds_read (fragment).
__global__ __launch_bounds__(256, 2) void scan_mfma(
    const unsigned short* __restrict__ imgh,  // [128][36][1024] bf16 bits
    const unsigned short* __restrict__ caph,  // [128][48][1024] bf16 bits
    float* __restrict__ out)                  // [128][128], out[i*128+c]
{
    // staging (double buffer): buf b at b*27648: simg 48*64=3072 B | scap 384*64=24576 B
    // phase2 (aliases staging, after final barrier):
    //   sS[8][36][49] f32 @0 (56448) | nrow @56448 | ncol @57600 | cr @59136 | cw @60288
    __shared__ __align__(16) unsigned char smem[61824];
    float (*sS)[RN][WN + 1] = (float (*)[RN][WN + 1])smem;
    float* snrow = (float*)(smem + 56448);   // [8][36]
    float* sncol = (float*)(smem + 57600);   // [8][48]
    float* scr   = (float*)(smem + 59136);   // [8][36]
    float* scw   = (float*)(smem + 60288);   // [8][48]

    const int t    = threadIdx.x;
    const int lane = t & 63;
    const int wid  = t >> 6;      // 0..3
    const int lr   = lane & 15;
    const int lg   = lane >> 4;   // 0..3

    const int i  = blockIdx.x;
    const int c0 = blockIdx.y * 8;

    const unsigned short* imgB = imgh + (size_t)i  * RN * DN;
    const unsigned short* capB = caph + (size_t)c0 * WN * DN;

    // ---- loop-invariant staging source offsets (elements) ----
    // cap: wave w stages slots [w*384 + j*64 + lane], j=0..5 ; slot -> row=slot>>2, g=slot&3
    int capoff[6];
#pragma unroll
    for (int j = 0; j < 6; ++j) {
        int slot = wid * 384 + j * 64 + lane;
        int row = slot >> 2, g = slot & 3;
        int sg = g ^ ((row >> 1) & 3);
        capoff[j] = row * DN + sg * 8;
    }
    // img: waves 0..2 stage slots [w*64 + lane] (rows 0..47; rows>=36 dummy data, never used)
    int islot = wid * 64 + lane;
    int irow = islot >> 2, ig = islot & 3;
    int isrc = (irow < RN) ? irow : irow - 24;
    int imgoff = isrc * DN + (ig ^ ((irow >> 1) & 3)) * 8;

    // ---- fragment read swizzle (byte offset of this lane's granule in its row) ----
    const int glo = ((lg ^ ((lr >> 1) & 3)) << 4);

    f32x4 acc[3][6];
#pragma unroll
    for (int rt = 0; rt < 3; ++rt)
#pragma unroll
        for (int ct = 0; ct < 6; ++ct) acc[rt][ct] = (f32x4)(0.f);

    auto stage = [&](int bsel, int d0) {
        char* bufp = (char*)smem + bsel * 27648;
        if (wid < 3) gld_lds16(imgB + imgoff + d0, bufp + wid * 1024);
        char* capd = bufp + 3072 + wid * 6144;
#pragma unroll
        for (int j = 0; j < 6; ++j)
            gld_lds16(capB + capoff[j] + d0, capd + j * 1024);
    };

    stage(0, 0);
    __syncthreads();

    for (int ch = 0; ch < 32; ++ch) {
        if (ch < 31) stage((ch & 1) ^ 1, (ch + 1) * 32);

        const char* bufp = (const char*)smem + (ch & 1) * 27648;
        const char* ap = bufp + lr * 64 + glo;
        short8 a0 = *(const short8*)(ap);
        short8 a1 = *(const short8*)(ap + 1024);
        short8 a2 = *(const short8*)(ap + 2048);
        const char* bp = bufp + 3072 + (wid * 96 + lr) * 64 + glo;
        short8 b[6];
#pragma unroll
        for (int ct = 0; ct < 6; ++ct) b[ct] = *(const short8*)(bp + ct * 1024);

        __builtin_amdgcn_s_setprio(1);
#pragma unroll
        for (int ct = 0; ct < 6; ++ct) {
            acc[0][ct] = __builtin_amdgcn_mfma_f32_16x16x32_bf16(a0, b[ct], acc[0][ct], 0, 0, 0);
            acc[1][ct] = __builtin_amdgcn_mfma_f32_16x16x32_bf16(a1, b[ct], acc[1][ct], 0, 0, 0);
            acc[2][ct] = __builtin_amdgcn_mfma_f32_16x16x32_bf16(a2, b[ct], acc[2][ct], 0, 0, 0);
        }
        __builtin_amdgcn_s_setprio(0);
        __syncthreads();
    }

    // write S tiles to LDS (aliases staging; behind the loop's final barrier)
    // C/D layout: col = lane&15, row = (lane>>4)*4 + reg   [m89-verified]
#pragma unroll
    for (int rt = 0; rt < 3; ++rt)
#pragma unroll
        for (int ct = 0; ct < 6; ++ct) {
            int cap = wid * 2 + ct / 3;
            int col = (ct % 3) * 16 + lr;
#pragma unroll
            for (int r = 0; r < 4; ++r) {
                int row = rt * 16 + lg * 4 + r;
                if (row < RN) sS[cap][row][col] = acc[rt][ct][r];
            }
        }
    __syncthreads();

    // ---- phase 2: per caption, l2 norms then softmax-weighted sums ----
    for (int idx = t; idx < 8 * WN; idx += 256) {
        int cap = idx / WN, w = idx % WN;
        float ss = 0.f;
        for (int r = 0; r < RN; ++r) { float l = leaky(sS[cap][r][w]); ss = fmaf(l, l, ss); }
        sncol[idx] = sqrtf(ss + EPSF) + EPSF;
    }
    for (int idx = t; idx < 8 * RN; idx += 256) {
        int cap = idx / RN, r = idx % RN;
        float ss = 0.f;
        for (int w = 0; w < WN; ++w) { float l = leaky(sS[cap][r][w]); ss = fmaf(l, l, ss); }
        snrow[idx] = sqrtf(ss + EPSF) + EPSF;
    }
    __syncthreads();

    // i2t: per row r, softmax over w of LAM*leaky(S)/ncol[w], weighted by S
    for (int idx = t; idx < 8 * RN; idx += 256) {
        int cap = idx / RN, r = idx % RN;
        const float* Sr = sS[cap][r];
        const float* nc = sncol + cap * WN;
        float m = -1e30f;
        for (int w = 0; w < WN; ++w) m = fmaxf(m, leaky(Sr[w]) / nc[w]);
        m *= LAMF;
        float se = 0.f, sw = 0.f;
        for (int w = 0; w < WN; ++w) {
            float e = __expf(LAMF * leaky(Sr[w]) / nc[w] - m);
            se += e;
            sw = fmaf(e, Sr[w], sw);
        }
        scr[idx] = sw / se;
    }
    // t2i: per col w, softmax over r of LAM*leaky(S)/nrow[r], weighted by S
    for (int idx = t; idx < 8 * WN; idx += 256) {
        int cap = idx / WN, w = idx % WN;
        const float* nr = snrow + cap * RN;
        float m = -1e30f;
        for (int r = 0; r < RN; ++r) m = fmaxf(m, leaky(sS[cap][r][w]) / nr[r]);
        m *= LAMF;
        float se = 0.f, sw = 0.f;
        for (int r = 0; r < RN; ++r) {
            float s = sS[cap][r][w];
            float e = __expf(LAMF * leaky(s) / nr[r] - m);
            se += e;
            sw = fmaf(e, s, sw);
        }
        scw[idx] = sw / se;
    }
    __syncthreads();

    if (t < 8) {
        float t2i = 0.f, i2t = 0.f;
        for (int w = 0; w < WN; ++w) t2i += scw[t * WN + w];
        for (int r = 0; r < RN; ++r) i2t += scr[t * RN + r];
        out[(size_t)i * CN + (c0 + t)] = t2i / (float)WN + i2t / (float)RN;
    }
}

// ---------- fp32 fallback (used only if ws too small) ----------
__global__ __launch_bounds__(256, 4) void scan_fused(
    const float* __restrict__ img_emb, const float* __restrict__ cap_emb,
    float* __restrict__ out)
{
    __shared__ float s_img[48][68];
    __shared__ float s_cap[48][68];
    __shared__ float s_S[RN][WN + 1];
    __shared__ float s_nrow[RN];
    __shared__ float s_ncol[WN];
    __shared__ float s_cw[WN];
    __shared__ float s_cr[RN];

    const int t = threadIdx.x;
    const int c = blockIdx.x & (CN - 1);
    const int i = blockIdx.x >> 7;
    const float* imgB = img_emb + (size_t)i * RN * DN;
    const float* capB = cap_emb + (size_t)c * WN * DN;
    const int ty = t >> 4, tx = t & 15;

    float4 acc[3][3];
#pragma unroll
    for (int a = 0; a < 3; ++a)
#pragma unroll
        for (int b = 0; b < 3; ++b) acc[a][b] = make_float4(0.f, 0.f, 0.f, 0.f);

    for (int d0 = 0; d0 < DN; d0 += 64) {
#pragma unroll
        for (int p = 0; p < 3; ++p) {
            int idx = t + p * 256, row = idx >> 4, col = (idx & 15) << 2;
            float4 v = make_float4(0.f, 0.f, 0.f, 0.f);
            if (row < RN) v = *(const float4*)(imgB + row * DN + d0 + col);
            *(float4*)&s_img[row][col] = v;
        }
#pragma unroll
        for (int p = 0; p < 3; ++p) {
            int idx = t + p * 256, row = idx >> 4, col = (idx & 15) << 2;
            *(float4*)&s_cap[row][col] = *(const float4*)(capB + row * DN + d0 + col);
        }
        __syncthreads();
        for (int d = 0; d < 64; d += 4) {
            float4 a0 = *(float4*)&s_img[ty][d], a1 = *(float4*)&s_img[ty + 16][d], a2 = *(float4*)&s_img[ty + 32][d];
            float4 b0 = *(float4*)&s_cap[tx][d], b1 = *(float4*)&s_cap[tx + 16][d], b2 = *(float4*)&s_cap[tx + 32][d];
#define F4(ac, aa, bb) ac.x=fmaf(aa.x,bb.x,ac.x); ac.y=fmaf(aa.y,bb.y,ac.y); ac.z=fmaf(aa.z,bb.z,ac.z); ac.w=fmaf(aa.w,bb.w,ac.w)
            F4(acc[0][0],a0,b0); F4(acc[0][1],a0,b1); F4(acc[0][2],a0,b2);
            F4(acc[1][0],a1,b0); F4(acc[1][1],a1,b1); F4(acc[1][2],a1,b2);
            F4(acc[2][0],a2,b0); F4(acc[2][1],a2,b1); F4(acc[2][2],a2,b2);
#undef F4
        }
        __syncthreads();
    }
#pragma unroll
    for (int a = 0; a < 3; ++a) {
        int r = ty + 16 * a;
        if (r < RN)
#pragma unroll
            for (int b = 0; b < 3; ++b) {
                float4 v = acc[a][b];
                s_S[r][tx + 16 * b] = (v.x + v.y) + (v.z + v.w);
            }
    }
    __syncthreads();
    if (t < RN) {
        float ss = 0.f;
        for (int w = 0; w < WN; ++w) { float l = leaky(s_S[t][w]); ss = fmaf(l, l, ss); }
        s_nrow[t] = sqrtf(ss + EPSF) + EPSF;
    } else if (t >= 64 && t < 64 + WN) {
        int w = t - 64; float ss = 0.f;
        for (int r = 0; r < RN; ++r) { float l = leaky(s_S[r][w]); ss = fmaf(l, l, ss); }
        s_ncol[w] = sqrtf(ss + EPSF) + EPSF;
    }
    __syncthreads();
    if (t < RN) {
        float m = -1e30f;
        for (int w = 0; w < WN; ++w) m = fmaxf(m, LAMF * leaky(s_S[t][w]) / s_ncol[w]);
        float se = 0.f, sw = 0.f;
        for (int w = 0; w < WN; ++w) {
            float e = __expf(LAMF * leaky(s_S[t][w]) / s_ncol[w] - m);
            se += e; sw = fmaf(e, s_S[t][w], sw);
        }
        s_cr[t] = sw / se;
    } else if (t >= 64 && t < 64 + WN) {
        int w = t - 64; float m = -1e30f;
        for (int r = 0; r < RN; ++r) m = fmaxf(m, LAMF * leaky(s_S[r][w]) / s_nrow[r]);
        float se = 0.f, sw = 0.f;
        for (int r = 0; r < RN; ++r) {
            float e = __expf(LAMF * leaky(s_S[r][w]) / s_nrow[r] - m);
            se += e; sw = fmaf(e, s_S[r][w], sw);
        }
        s_cw[w] = sw / se;
    }
    __syncthreads();
    if (t == 0) {
        float t2i = 0.f, i2t = 0.f;
        for (int w = 0; w < WN; ++w) t2i += s_cw[w];
        for (int r = 0; r < RN; ++r) i2t += s_cr[r];
        out[(size_t)i * CN + c] = t2i / (float)WN + i2t / (float)RN;
    }
}

extern "C" void kernel_launch(void* const* d_in, const int* in_sizes, int n_in,
                              void* d_out, int out_size, void* d_ws, size_t ws_size,
                              hipStream_t stream) {
    const float* img = (const float*)d_in[0];
    const float* cap = (const float*)d_in[2];
    float* out = (float*)d_out;

    const size_t n_img = (size_t)IN * RN * DN;   // 4718592
    const size_t n_cap = (size_t)CN * WN * DN;   // 6291456
    const size_t need  = (n_img + n_cap) * 2;

    if (ws_size >= need) {
        unsigned short* imgh = (unsigned short*)d_ws;
        unsigned short* caph = imgh + n_img;
        int n4i = (int)(n_img / 4), n4c = (int)(n_cap / 4);
        hipLaunchKernelGGL(cvt_bf16, dim3((n4i + 255) / 256), dim3(256), 0, stream, img, imgh, n4i);
        hipLaunchKernelGGL(cvt_bf16, dim3((n4c + 255) / 256), dim3(256), 0, stream, cap, caph, n4c);
        hipLaunchKernelGGL(scan_mfma, dim3(IN, CN / 8), dim3(256), 0, stream, imgh, caph, out);
    } else {
        hipLaunchKernelGGL(scan_fused, dim3(IN * CN), dim3(256), 0, stream, img, cap, out);
    }
}

// Round 4
// 104.725 us; speedup vs baseline: 10.9843x; 2.0769x over previous
//
#include <hip/hip_runtime.h>
#include <hip/hip_bf16.h>

// SCAN similarity: out[i,c] = t2i[c,i] + i2t[c,i]
// g (global sim) cancels in the renormalization -> img_mean/cap_mean unused.
// bf16 MFMA, 4img x 4cap blocks, global_load_lds dbuf, XOR-swizzled LDS,
// two-round in-LDS softmax epilogue (single-pass, bounded arg => no max).

#define EPSF 1e-8f
#define LAMF 9.0f

constexpr int IN = 128, CN = 128, RN = 36, WN = 48, DN = 1024;
constexpr size_t NIMG = (size_t)IN * RN * DN;   // 4718592 elems

using short8 = __attribute__((ext_vector_type(8))) short;
using f32x4  = __attribute__((ext_vector_type(4))) float;

__device__ __forceinline__ float leaky(float x) { return x > 0.f ? x : 0.1f * x; }

__device__ __forceinline__ unsigned short f2bf(float f) {
    unsigned int b = __float_as_uint(f);
    b += 0x7FFFu + ((b >> 16) & 1u);          // round-to-nearest-even
    return (unsigned short)(b >> 16);
}

__device__ __forceinline__ void gld_lds16(const unsigned short* g, void* l) {
    __builtin_amdgcn_global_load_lds(
        (const __attribute__((address_space(1))) unsigned int*)g,
        (__attribute__((address_space(3))) unsigned int*)l,
        16, 0, 0);
}

// ---------- preprocess: f32 -> bf16 ----------
__global__ void cvt_bf16(const float* __restrict__ in, unsigned short* __restrict__ out, int n4) {
    int idx = blockIdx.x * blockDim.x + threadIdx.x;
    if (idx >= n4) return;
    float4 v = ((const float4*)in)[idx];
    ushort4 o;
    o.x = f2bf(v.x); o.y = f2bf(v.y); o.z = f2bf(v.z); o.w = f2bf(v.w);
    ((ushort4*)out)[idx] = o;
}

// ---------- main MFMA kernel ----------
// block = 4 images (blockIdx.x*4..) x 4 captions (blockIdx.y*4..); 8 waves.
// Wave wid: wi=wid>>1 (image), wc=wid&1 (cap pair) -> S panel 48(36 real)x96.
// K chunk = 32. LDS rows 64 B = 4x16B granules, XOR-swizzle (row>>1)&3 applied
// on the pre-swizzled GLOBAL source and on the ds_read granule (rule 21).
__global__ __launch_bounds__(512, 4) void scan_mfma(
    const unsigned short* __restrict__ wsb,   // imgh @0 [128][36][1024], caph @NIMG [128][48][1024]
    float* __restrict__ out)                  // [128][128], out[i*128+c]
{
    // staging dbuf: 2 x 24576 B (img 192 rows x 64 B | cap 192 rows x 64 B)
    // phase2 (aliases staging, behind GEMM's final barrier):
    //   sS[8][36][49] @0 (56448) | sncol @56448 (1536) | snrow @57984 (1152)
    //   scw @59136 (1536) | scr @60672 (1152)  -> total 61824
    __shared__ __align__(16) unsigned char smem[61824];
    float (*sS)[RN][WN + 1] = (float (*)[RN][WN + 1])smem;
    float* sncol = (float*)(smem + 56448);   // [8][48] : LAMF / col_norm
    float* snrow = (float*)(smem + 57984);   // [8][36] : LAMF / row_norm
    float* scw   = (float*)(smem + 59136);   // [8][48]
    float* scr   = (float*)(smem + 60672);   // [8][36]

    const int t    = threadIdx.x;
    const int lane = t & 63;
    const int wid  = t >> 6;      // 0..7
    const int lr   = lane & 15;
    const int lg   = lane >> 4;   // 0..3
    const int wi   = wid >> 1;    // image 0..3
    const int wc   = wid & 1;     // cap pair 0..1

    const int bi = blockIdx.x;    // image block (4 images)
    const int bc = blockIdx.y;    // caption block (4 captions)

    // ---- loop-invariant staging source offsets (elements, relative to wsb) ----
    // 24 segments of 1024 B per buffer; wave wid stages segments wid, wid+8, wid+16.
    size_t soff[3];
#pragma unroll
    for (int j = 0; j < 3; ++j) {
        int G = (wid + 8 * j) * 64 + lane;   // granule id 0..1535
        int row = G >> 2, g = G & 3;
        if (row < 192) {                      // img region: 4 imgs x 48 rows
            int ii = row / 48, rin = row % 48;
            int rsrc = (rin < RN) ? rin : rin - 12;   // dummy rows (discarded later)
            int sg = g ^ ((row >> 1) & 3);
            soff[j] = ((size_t)(bi * 4 + ii) * RN + rsrc) * DN + sg * 8;
        } else {                              // cap region: 4 caps x 48 rows
            int crow = row - 192;
            int ci = crow / 48, rin = crow % 48;
            int sg = g ^ ((crow >> 1) & 3);
            soff[j] = NIMG + ((size_t)(bc * 4 + ci) * WN + rin) * DN + sg * 8;
        }
    }

    // fragment read swizzle (byte offset of this lane's 16B granule within its row)
    const int glo = ((lg ^ ((lr >> 1) & 3)) << 4);

    f32x4 acc[3][6];
#pragma unroll
    for (int rt = 0; rt < 3; ++rt)
#pragma unroll
        for (int ct = 0; ct < 6; ++ct) acc[rt][ct] = (f32x4)(0.f);

    auto stage = [&](int bsel, int d0) {
        char* bufp = (char*)smem + bsel * 24576;
#pragma unroll
        for (int j = 0; j < 3; ++j)
            gld_lds16(wsb + soff[j] + d0, bufp + (wid + 8 * j) * 1024);
    };

    stage(0, 0);
    __syncthreads();

    for (int ch = 0; ch < 32; ++ch) {
        if (ch < 31) stage((ch & 1) ^ 1, (ch + 1) * 32);

        const char* bufp = (const char*)smem + (ch & 1) * 24576;
        const char* ap = bufp + (wi * 48 + lr) * 64 + glo;            // rt stride 1024
        short8 a0 = *(const short8*)(ap);
        short8 a1 = *(const short8*)(ap + 1024);
        short8 a2 = *(const short8*)(ap + 2048);
        const char* bp = bufp + 12288 + (wc * 96 + lr) * 64 + glo;    // ct stride 1024
        short8 b[6];
#pragma unroll
        for (int ct = 0; ct < 6; ++ct) b[ct] = *(const short8*)(bp + ct * 1024);

        __builtin_amdgcn_s_setprio(1);
#pragma unroll
        for (int ct = 0; ct < 6; ++ct) {
            acc[0][ct] = __builtin_amdgcn_mfma_f32_16x16x32_bf16(a0, b[ct], acc[0][ct], 0, 0, 0);
            acc[1][ct] = __builtin_amdgcn_mfma_f32_16x16x32_bf16(a1, b[ct], acc[1][ct], 0, 0, 0);
            acc[2][ct] = __builtin_amdgcn_mfma_f32_16x16x32_bf16(a2, b[ct], acc[2][ct], 0, 0, 0);
        }
        __builtin_amdgcn_s_setprio(0);
        __syncthreads();
    }

    // ---- epilogue: two rounds of 8 (i,c) tiles each ----
    // round r handles images bi*4 + r*2 + {0,1}; tile lt = (wi&1)*4 + wc*2 + ct/3
#pragma unroll
    for (int round = 0; round < 2; ++round) {
        // write S tiles for this round's waves (C/D: col=lane&15, row=(lane>>4)*4+reg)
        if ((wi >> 1) == round) {
            const int ltb = (wi & 1) * 4 + wc * 2;
#pragma unroll
            for (int rt = 0; rt < 3; ++rt)
#pragma unroll
                for (int ct = 0; ct < 6; ++ct) {
                    int lt = ltb + ct / 3;
                    int col = (ct % 3) * 16 + lr;
#pragma unroll
                    for (int r = 0; r < 4; ++r) {
                        int row = rt * 16 + lg * 4 + r;
                        if (row < RN) sS[lt][row][col] = acc[rt][ct][r];
                    }
                }
        }
        if (round == 1 && t < 8) {
            // finalize round 0 (reads scr/scw; disjoint from sS writes above)
            float s1 = 0.f, s2 = 0.f;
            for (int w = 0; w < WN; ++w) s1 += scw[t * WN + w];
            for (int r = 0; r < RN; ++r) s2 += scr[t * RN + r];
            int i = bi * 4 + (t >> 2), c = bc * 4 + (t & 3);
            out[(size_t)i * CN + c] = s1 / (float)WN + s2 / (float)RN;
        }
        __syncthreads();

        // inverse l2 norms (scaled by LAMF)
        if (t < 8 * WN) {                       // col norms over r
            int tile = t / WN, w = t % WN;
            float ss = 0.f;
            for (int r = 0; r < RN; ++r) { float l = leaky(sS[tile][r][w]); ss = fmaf(l, l, ss); }
            sncol[t] = LAMF / (sqrtf(ss + EPSF) + EPSF);
        }
        if (t < 8 * RN) {                       // row norms over w
            int tile = t / RN, r = t % RN;
            float ss = 0.f;
            for (int w = 0; w < WN; ++w) { float l = leaky(sS[tile][r][w]); ss = fmaf(l, l, ss); }
            snrow[t] = LAMF / (sqrtf(ss + EPSF) + EPSF);
        }
        __syncthreads();

        // single-pass softmaxes (arg = leaky(S) * LAMF/n is bounded by 9 -> no max pass)
        if (t < 8 * RN) {                       // i2t: softmax over w per row r
            int tile = t / RN, r = t % RN;
            const float* Sr = sS[tile][r];
            const float* ic = sncol + tile * WN;
            float se = 0.f, sw = 0.f;
            for (int w = 0; w < WN; ++w) {
                float s = Sr[w];
                float e = __expf(leaky(s) * ic[w]);
                se += e;
                sw = fmaf(e, s, sw);
            }
            scr[t] = sw / se;
        }
        if (t < 8 * WN) {                       // t2i: softmax over r per col w
            int tile = t / WN, w = t % WN;
            const float* ir = snrow + tile * RN;
            float se = 0.f, sw = 0.f;
            for (int r = 0; r < RN; ++r) {
                float s = sS[tile][r][w];
                float e = __expf(leaky(s) * ir[r]);
                se += e;
                sw = fmaf(e, s, sw);
            }
            scw[t] = sw / se;
        }
        __syncthreads();

        if (round == 1 && t < 8) {
            // finalize round 1
            float s1 = 0.f, s2 = 0.f;
            for (int w = 0; w < WN; ++w) s1 += scw[t * WN + w];
            for (int r = 0; r < RN; ++r) s2 += scr[t * RN + r];
            int i = bi * 4 + 2 + (t >> 2), c = bc * 4 + (t & 3);
            out[(size_t)i * CN + c] = s1 / (float)WN + s2 / (float)RN;
        }
    }
}

// ---------- fp32 fallback (used only if ws too small) ----------
__global__ __launch_bounds__(256, 4) void scan_fused(
    const float* __restrict__ img_emb, const float* __restrict__ cap_emb,
    float* __restrict__ out)
{
    __shared__ float s_img[48][68];
    __shared__ float s_cap[48][68];
    __shared__ float s_S[RN][WN + 1];
    __shared__ float s_nrow[RN];
    __shared__ float s_ncol[WN];
    __shared__ float s_cw[WN];
    __shared__ float s_cr[RN];

    const int t = threadIdx.x;
    const int c = blockIdx.x & (CN - 1);
    const int i = blockIdx.x >> 7;
    const float* imgB = img_emb + (size_t)i * RN * DN;
    const float* capB = cap_emb + (size_t)c * WN * DN;
    const int ty = t >> 4, tx = t & 15;

    float4 acc[3][3];
#pragma unroll
    for (int a = 0; a < 3; ++a)
#pragma unroll
        for (int b = 0; b < 3; ++b) acc[a][b] = make_float4(0.f, 0.f, 0.f, 0.f);

    for (int d0 = 0; d0 < DN; d0 += 64) {
#pragma unroll
        for (int p = 0; p < 3; ++p) {
            int idx = t + p * 256, row = idx >> 4, col = (idx & 15) << 2;
            float4 v = make_float4(0.f, 0.f, 0.f, 0.f);
            if (row < RN) v = *(const float4*)(imgB + row * DN + d0 + col);
            *(float4*)&s_img[row][col] = v;
        }
#pragma unroll
        for (int p = 0; p < 3; ++p) {
            int idx = t + p * 256, row = idx >> 4, col = (idx & 15) << 2;
            *(float4*)&s_cap[row][col] = *(const float4*)(capB + row * DN + d0 + col);
        }
        __syncthreads();
        for (int d = 0; d < 64; d += 4) {
            float4 a0 = *(float4*)&s_img[ty][d], a1 = *(float4*)&s_img[ty + 16][d], a2 = *(float4*)&s_img[ty + 32][d];
            float4 b0 = *(float4*)&s_cap[tx][d], b1 = *(float4*)&s_cap[tx + 16][d], b2 = *(float4*)&s_cap[tx + 32][d];
#define F4(ac, aa, bb) ac.x=fmaf(aa.x,bb.x,ac.x); ac.y=fmaf(aa.y,bb.y,ac.y); ac.z=fmaf(aa.z,bb.z,ac.z); ac.w=fmaf(aa.w,bb.w,ac.w)
            F4(acc[0][0],a0,b0); F4(acc[0][1],a0,b1); F4(acc[0][2],a0,b2);
            F4(acc[1][0],a1,b0); F4(acc[1][1],a1,b1); F4(acc[1][2],a1,b2);
            F4(acc[2][0],a2,b0); F4(acc[2][1],a2,b1); F4(acc[2][2],a2,b2);
#undef F4
        }
        __syncthreads();
    }
#pragma unroll
    for (int a = 0; a < 3; ++a) {
        int r = ty + 16 * a;
        if (r < RN)
#pragma unroll
            for (int b = 0; b < 3; ++b) {
                float4 v = acc[a][b];
                s_S[r][tx + 16 * b] = (v.x + v.y) + (v.z + v.w);
            }
    }
    __syncthreads();
    if (t < RN) {
        float ss = 0.f;
        for (int w = 0; w < WN; ++w) { float l = leaky(s_S[t][w]); ss = fmaf(l, l, ss); }
        s_nrow[t] = sqrtf(ss + EPSF) + EPSF;
    } else if (t >= 64 && t < 64 + WN) {
        int w = t - 64; float ss = 0.f;
        for (int r = 0; r < RN; ++r) { float l = leaky(s_S[r][w]); ss = fmaf(l, l, ss); }
        s_ncol[w] = sqrtf(ss + EPSF) + EPSF;
    }
    __syncthreads();
    if (t < RN) {
        float se = 0.f, sw = 0.f;
        for (int w = 0; w < WN; ++w) {
            float e = __expf(LAMF * leaky(s_S[t][w]) / s_ncol[w]);
            se += e; sw = fmaf(e, s_S[t][w], sw);
        }
        s_cr[t] = sw / se;
    } else if (t >= 64 && t < 64 + WN) {
        int w = t - 64;
        float se = 0.f, sw = 0.f;
        for (int r = 0; r < RN; ++r) {
            float e = __expf(LAMF * leaky(s_S[r][w]) / s_nrow[r]);
            se += e; sw = fmaf(e, s_S[r][w], sw);
        }
        s_cw[w] = sw / se;
    }
    __syncthreads();
    if (t == 0) {
        float t2i = 0.f, i2t = 0.f;
        for (int w = 0; w < WN; ++w) t2i += s_cw[w];
        for (int r = 0; r < RN; ++r) i2t += s_cr[r];
        out[(size_t)i * CN + c] = t2i / (float)WN + i2t / (float)RN;
    }
}

extern "C" void kernel_launch(void* const* d_in, const int* in_sizes, int n_in,
                              void* d_out, int out_size, void* d_ws, size_t ws_size,
                              hipStream_t stream) {
    const float* img = (const float*)d_in[0];
    const float* cap = (const float*)d_in[2];
    float* out = (float*)d_out;

    const size_t n_img = NIMG;                   // 4718592
    const size_t n_cap = (size_t)CN * WN * DN;   // 6291456
    const size_t need  = (n_img + n_cap) * 2;

    if (ws_size >= need) {
        unsigned short* imgh = (unsigned short*)d_ws;
        unsigned short* caph = imgh + n_img;
        int n4i = (int)(n_img / 4), n4c = (int)(n_cap / 4);
        hipLaunchKernelGGL(cvt_bf16, dim3((n4i + 255) / 256), dim3(256), 0, stream, img, imgh, n4i);
        hipLaunchKernelGGL(cvt_bf16, dim3((n4c + 255) / 256), dim3(256), 0, stream, cap, caph, n4c);
        hipLaunchKernelGGL(scan_mfma, dim3(IN / 4, CN / 4), dim3(512), 0, stream, imgh, out);
    } else {
        hipLaunchKernelGGL(scan_fused, dim3(IN * CN), dim3(256), 0, stream, img, cap, out);
    }
}